// Round 2
// baseline (99.106 us; speedup 1.0000x reference)
//
#include <hip/hip_runtime.h>

// RationalRMSNorm: x [B,S,H=4096] fp32, weight [H] fp32 -> out fp32
// One block (256 threads) per row. Each thread: 4x float4 = 16 elements,
// held in registers between the reduction and the scale+store pass.

constexpr int H = 4096;
constexpr int THREADS = 256;
constexpr int VECS_PER_THREAD = H / (THREADS * 4); // 4

__global__ __launch_bounds__(THREADS)
void rational_rmsnorm_kernel(const float* __restrict__ x,
                             const float* __restrict__ w,
                             float* __restrict__ out) {
    const long long row = blockIdx.x;
    const float4* xr = reinterpret_cast<const float4*>(x + row * (long long)H);
    float4* outr     = reinterpret_cast<float4*>(out + row * (long long)H);
    const float4* wv4 = reinterpret_cast<const float4*>(w);

    const int t = threadIdx.x;

    float4 v[VECS_PER_THREAD];
    float sumsq = 0.0f;
#pragma unroll
    for (int i = 0; i < VECS_PER_THREAD; ++i) {
        v[i] = xr[i * THREADS + t];
        sumsq += v[i].x * v[i].x + v[i].y * v[i].y
               + v[i].z * v[i].z + v[i].w * v[i].w;
    }

    // wave-64 butterfly-free down-reduce
#pragma unroll
    for (int off = 32; off > 0; off >>= 1)
        sumsq += __shfl_down(sumsq, off, 64);

    __shared__ float partial[THREADS / 64];
    __shared__ float s_inv;
    const int wave = t >> 6;
    if ((t & 63) == 0) partial[wave] = sumsq;
    __syncthreads();

    if (t == 0) {
        float total = partial[0] + partial[1] + partial[2] + partial[3];
        // variance = mean, clipped
        float variance = total * (1.0f / (float)H);
        variance = fmaxf(variance, 1e-8f);
        // _babylonian_rsqrt(variance + EPS), replicated op-for-op
        float xs = variance + 1e-6f;
        xs = fmaxf(xs, 1e-8f);
        float log_x = log10f(xs + 1.0f);
        float scale_exp = floorf(log_x / 2.0f) * 2.0f;
        float scale = powf(10.0f, scale_exp);
        float x_norm = xs / scale;
        float y = 0.1f;
        float half_x = 0.5f * x_norm;
#pragma unroll
        for (int i = 0; i < 10; ++i)
            y = y * (1.5f - half_x * (y * y));
        float inv_sqrt_scale = powf(10.0f, -scale_exp / 2.0f);
        s_inv = y * inv_sqrt_scale;
    }
    __syncthreads();

    const float inv = s_inv;
#pragma unroll
    for (int i = 0; i < VECS_PER_THREAD; ++i) {
        float4 wv = wv4[i * THREADS + t];
        float4 o;
        o.x = v[i].x * inv * wv.x;
        o.y = v[i].y * inv * wv.y;
        o.z = v[i].z * inv * wv.z;
        o.w = v[i].w * inv * wv.w;
        outr[i * THREADS + t] = o;
    }
}

extern "C" void kernel_launch(void* const* d_in, const int* in_sizes, int n_in,
                              void* d_out, int out_size, void* d_ws, size_t ws_size,
                              hipStream_t stream) {
    const float* x = (const float*)d_in[0];
    const float* w = (const float*)d_in[1];
    float* out = (float*)d_out;
    const int nrows = in_sizes[0] / H; // B*S = 16384
    rational_rmsnorm_kernel<<<nrows, THREADS, 0, stream>>>(x, w, out);
}

// Round 4
// 91.937 us; speedup vs baseline: 1.0780x; 1.0780x over previous
//
#include <hip/hip_runtime.h>

// RationalRMSNorm: x [B,S,H=4096] fp32, weight [H] fp32 -> out fp32
// One block (256 threads) per row; 4x f32x4 per thread held in registers.
// Nontemporal loads/stores for the streamed x/out (no reuse); weight via
// normal loads (L2-resident, reused by all 16384 blocks).

typedef float f32x4 __attribute__((ext_vector_type(4)));

constexpr int H = 4096;
constexpr int THREADS = 256;
constexpr int VECS_PER_THREAD = H / (THREADS * 4); // 4

__global__ __launch_bounds__(THREADS)
void rational_rmsnorm_kernel(const float* __restrict__ x,
                             const float* __restrict__ w,
                             float* __restrict__ out) {
    const long long row = blockIdx.x;
    const f32x4* xr = reinterpret_cast<const f32x4*>(x + row * (long long)H);
    f32x4* outr     = reinterpret_cast<f32x4*>(out + row * (long long)H);
    const f32x4* wv4 = reinterpret_cast<const f32x4*>(w);

    const int t = threadIdx.x;

    f32x4 v[VECS_PER_THREAD];
    float sumsq = 0.0f;
#pragma unroll
    for (int i = 0; i < VECS_PER_THREAD; ++i) {
        v[i] = __builtin_nontemporal_load(&xr[i * THREADS + t]);
        sumsq += v[i].x * v[i].x + v[i].y * v[i].y
               + v[i].z * v[i].z + v[i].w * v[i].w;
    }

    // wave-64 down-reduce
#pragma unroll
    for (int off = 32; off > 0; off >>= 1)
        sumsq += __shfl_down(sumsq, off, 64);

    __shared__ float partial[THREADS / 64];
    const int wave = t >> 6;
    if ((t & 63) == 0) partial[wave] = sumsq;
    __syncthreads();

    // Every thread redundantly computes the scalar chain (removes the 2nd
    // barrier + serial section; ~40 VALU ops, VALU is ~5% busy).
    float total = partial[0] + partial[1] + partial[2] + partial[3];
    float variance = total * (1.0f / (float)H);
    variance = fmaxf(variance, 1e-8f);
    // _babylonian_rsqrt(variance + EPS), replicated op-for-op
    float xs = variance + 1e-6f;
    xs = fmaxf(xs, 1e-8f);
    float log_x = log10f(xs + 1.0f);
    float scale_exp = floorf(log_x / 2.0f) * 2.0f;
    float scale = powf(10.0f, scale_exp);
    float x_norm = xs / scale;
    float y = 0.1f;
    float half_x = 0.5f * x_norm;
#pragma unroll
    for (int i = 0; i < 10; ++i)
        y = y * (1.5f - half_x * (y * y));
    float inv_sqrt_scale = powf(10.0f, -scale_exp / 2.0f);
    const float inv = y * inv_sqrt_scale;

#pragma unroll
    for (int i = 0; i < VECS_PER_THREAD; ++i) {
        f32x4 wv = wv4[i * THREADS + t];
        f32x4 o = v[i] * inv * wv;
        __builtin_nontemporal_store(o, &outr[i * THREADS + t]);
    }
}

extern "C" void kernel_launch(void* const* d_in, const int* in_sizes, int n_in,
                              void* d_out, int out_size, void* d_ws, size_t ws_size,
                              hipStream_t stream) {
    const float* x = (const float*)d_in[0];
    const float* w = (const float*)d_in[1];
    float* out = (float*)d_out;
    const int nrows = in_sizes[0] / H; // B*S = 16384
    rational_rmsnorm_kernel<<<nrows, THREADS, 0, stream>>>(x, w, out);
}